// Round 13
// baseline (1588.163 us; speedup 1.0000x reference)
//
#include <hip/hip_runtime.h>

#define TSTEPS 2048
#define NBATCH 512
#define H1 64
#define H2 16

typedef _Float16 h2v __attribute__((ext_vector_type(2)));

__device__ __forceinline__ float fsig(float x) {
    return __builtin_amdgcn_rcpf(1.0f + __builtin_amdgcn_exp2f(-1.4426950408889634f * x));
}
__device__ __forceinline__ float ftanh(float x) {
    // tanh(x) = 1 - 2/(exp2(2x*log2e)+1); saturates correctly at +-inf
    return 1.0f - 2.0f * __builtin_amdgcn_rcpf(1.0f + __builtin_amdgcn_exp2f(2.8853900817779268f * x));
}
// branchless: k2==1 -> sigmoid(x); k2==2 -> tanh(x) = 2*sig(2x)-1
__device__ __forceinline__ float act(float x, float k2) {
    return k2 * fsig(k2 * x) - (k2 - 1.0f);
}

#if __has_builtin(__builtin_amdgcn_fdot2)
__device__ __forceinline__ float dot2(int wp, int hp, float acc) {
    return __builtin_amdgcn_fdot2(__builtin_bit_cast(h2v, wp),
                                  __builtin_bit_cast(h2v, hp), acc, false);
}
#else
__device__ __forceinline__ float dot2(int wp, int hp, float acc) {
    h2v a = __builtin_bit_cast(h2v, wp), b = __builtin_bit_cast(h2v, hp);
    return acc + (float)a.x * (float)b.x + (float)a.y * (float)b.y;
}
#endif

__device__ __forceinline__ int packh2(float a, float b) {
    h2v v; v.x = (_Float16)a; v.y = (_Float16)b;
    return __builtin_bit_cast(int, v);
}
template<int CTRL>
__device__ __forceinline__ float dpp_bcast(float v) {   // quad broadcast
    int r = __builtin_amdgcn_mov_dpp(__float_as_int(v), CTRL, 0xF, 0xF, true);
    return __int_as_float(r);
}

// TWO WAVES PER BATCH, k-split, ONE __syncthreads per step.
// r12 post-mortem: barrier-impl swap changed nothing (7.4e-2 -> 7.2e-2), so
// the fence theory was wrong. Real bug found by re-audit under that
// constraint: the TAIL FLUSH raced -- ring row 31 (t=2047) is written by
// wave 0 AFTER the loop's final barrier, and wave 1 read it in the tail with
// no barrier in between, publishing stale h2(2015) as out[:,2047,:]
// (max|h2(2047)-h2(2015)| ~ 7e-2 = the observed error, both rounds).
// Fix: one __syncthreads() between loop exit and tail flush. Everything else
// identical to r12. In-loop ring reads are >=16 barriers behind writes (safe).
__global__ void __launch_bounds__(128, 1)
__attribute__((amdgpu_waves_per_eu(1, 1)))
lstm2_fused(const float* __restrict__ x,      // [512, 2048, 1]
            const float* __restrict__ w_ih1,  // [256, 1]
            const float* __restrict__ w_hh1,  // [256, 64]
            const float* __restrict__ b_ih1,  // [256]
            const float* __restrict__ b_hh1,  // [256]
            const float* __restrict__ w_ih2,  // [64, 64]
            const float* __restrict__ w_hh2,  // [64, 16]
            const float* __restrict__ b_ih2,  // [64]
            const float* __restrict__ b_hh2,  // [64]
            float* __restrict__ out)          // [512, 2048, 16]
{
    const int tid  = threadIdx.x;
    const int w    = tid >> 6;        // wave 0/1
    const int lane = tid & 63;
    const int b    = blockIdx.x;      // 1 batch per block

    __shared__ __align__(16) float    x_lds[TSTEPS];     // 8 KB
    __shared__ __align__(16) _Float16 h1s[2][H1];        // per-wave h1 replica
    __shared__ __align__(16) _Float16 h2s[2][H2];        // per-wave h2 replica
    __shared__ __align__(16) float    xch[2][2][64][4];  // [parity][wave][lane] L1 partials
    __shared__ __align__(16) float    xch2[2][2][64];    // L2 partials
    __shared__ __align__(16) float    ring[32][H2];      // output ring

    // ---- zero state, stage x[b,:] ----
    if (tid < 64) ((int*)h1s)[tid] = 0;
    else if (tid < 80) ((int*)h2s)[tid - 64] = 0;
    {
        const float4* xs = (const float4*)(x + (size_t)b * TSTEPS);
        float4* xd = (float4*)x_lds;
        #pragma unroll
        for (int i = 0; i < 4; ++i) xd[tid + 128 * i] = xs[tid + 128 * i];
    }
    __syncthreads();

    // ---- L1 weights: lane j owns channel j, all 4 gates, k in [32w, 32w+32) ----
    int   w1[4][16];
    float wx1[4], bs1[4];
    #pragma unroll
    for (int g = 0; g < 4; ++g) {
        const int r = g * H1 + lane;
        const float* wr = w_hh1 + (size_t)r * H1 + 32 * w;
        #pragma unroll
        for (int t = 0; t < 16; ++t) w1[g][t] = packh2(wr[2 * t], wr[2 * t + 1]);
        wx1[g] = w_ih1[r];
        bs1[g] = b_ih1[r] + b_hh1[r];
    }
    // ---- L2 weights: lane -> (m = lane>>2, g2 = lane&3), k-half [32w,32w+32) ----
    const int m  = lane >> 2;
    const int g2 = lane & 3;
    const int r2 = g2 * H2 + m;
    int w2[16], wh2[4];
    #pragma unroll
    for (int t = 0; t < 16; ++t)
        w2[t] = packh2(w_ih2[(size_t)r2 * H1 + 32 * w + 2 * t],
                       w_ih2[(size_t)r2 * H1 + 32 * w + 2 * t + 1]);
    #pragma unroll
    for (int t = 0; t < 4; ++t)
        wh2[t] = packh2(w_hh2[(size_t)r2 * H2 + 8 * w + 2 * t],
                        w_hh2[(size_t)r2 * H2 + 8 * w + 2 * t + 1]);
    const float bs2 = b_ih2[r2] + b_hh2[r2];
    const float k22 = (g2 == 2) ? 2.0f : 1.0f;

    float c1 = 0.0f;                  // channel j cell (replicated in both waves)
    float c2 = 0.0f;                  // channel m cell (replicated per quad + wave)
    float* outb = out + (size_t)b * TSTEPS * H2;

    // own half of the h1 replica: bytes [64w, 64w+64) = this wave's k-range
    const int4* hs = ((const int4*)h1s[w]) + 4 * w;

    // per-pair dots: 4 L1 chains + 1 L2 chain (a_{t&3})
#define DOTP(T, HV)  do {                                   \
        ai = dot2(w1[0][T], HV, ai);                        \
        af = dot2(w1[1][T], HV, af);                        \
        ag = dot2(w1[2][T], HV, ag);                        \
        ao = dot2(w1[3][T], HV, ao);                        \
        if ((T & 3) == 0) a0 = dot2(w2[T], HV, a0);         \
        if ((T & 3) == 1) a1 = dot2(w2[T], HV, a1);         \
        if ((T & 3) == 2) a2 = dot2(w2[T], HV, a2);         \
        if ((T & 3) == 3) a3 = dot2(w2[T], HV, a3);         \
    } while (0)

    for (int p = 0; p <= TSTEPS; ++p) {
        // ---- output flush: every 16 steps, rows written 16-31 steps ago ----
        const int tau_f = p - 1;
        if (tau_f >= 31 && (tau_f & 15) == 15) {
            const int tau0 = (tau_f & ~15) - 16;
            const int tt = tau0 + (tid >> 3), ch0 = (tid & 7) * 2;
            float2 v = *(const float2*)&ring[tt & 31][ch0];
            *(float2*)(outb + (size_t)tt * H2 + ch0) = v;    // background stores
        }

        // ---- read own replica: h1(p-1) half + h2(p-2) quarter (same-wave FIFO) ----
        int4 hA = hs[0], hB = hs[1], hC = hs[2], hD = hs[3];
        int4 hq = ((const int4*)h2s[w])[w];

        float ai = 0.f, af = 0.f, ag = 0.f, ao = 0.f;
        float a0 = 0.f, a1 = 0.f, a2 = 0.f, a3 = 0.f;
        DOTP(0, hA.x);  DOTP(1, hA.y);  DOTP(2, hA.z);  DOTP(3, hA.w);
        DOTP(4, hB.x);  DOTP(5, hB.y);  DOTP(6, hB.z);  DOTP(7, hB.w);
        DOTP(8, hC.x);  DOTP(9, hC.y);  DOTP(10, hC.z); DOTP(11, hC.w);
        DOTP(12, hD.x); DOTP(13, hD.y); DOTP(14, hD.z); DOTP(15, hD.w);
        // L2 recurrent (h2) quarter: pairs 4w..4w+3
        a0 = dot2(wh2[0], hq.x, a0);
        a1 = dot2(wh2[1], hq.y, a1);
        a2 = dot2(wh2[2], hq.z, a2);
        a3 = dot2(wh2[3], hq.w, a3);
        const float my2 = (a0 + a1) + (a2 + a3);

        // ---- exchange partials (parity-double-buffered; ONE full barrier) ----
        const int pb = p & 1;
        float4 mine = {ai, af, ag, ao};
        *(float4*)&xch[pb][w][lane][0] = mine;
        xch2[pb][w][lane] = my2;
        __syncthreads();
        float4 othr = *(const float4*)&xch[pb][w ^ 1][lane][0];
        float  o2   = xch2[pb][w ^ 1][lane];

        // ===== Layer 1 finish, timestep p (both waves, replicated) =====
        if (p < TSTEPS) {
            const float xv = x_lds[p];
            float pi = ai + othr.x + bs1[0] + wx1[0] * xv;
            float pf = af + othr.y + bs1[1] + wx1[1] * xv;
            float pg = ag + othr.z + bs1[2] + wx1[2] * xv;
            float po = ao + othr.w + bs1[3] + wx1[3] * xv;
            float gi = fsig(pi), gf = fsig(pf), gg = ftanh(pg), go = fsig(po);
            c1 = gf * c1 + gi * gg;
            float h1n = go * ftanh(c1);
            h1s[w][lane] = (_Float16)h1n;       // own replica; read next iter (FIFO)
        }

        // ===== Layer 2 finish, timestep p-1 (both waves, replicated) =====
        if (p >= 1) {
            float pre2 = my2 + o2 + bs2;
            float av = act(pre2, k22);
            float gi = dpp_bcast<0x00>(av);     // quad holds (i,f,g,o) of channel m
            float gf = dpp_bcast<0x55>(av);
            float gg = dpp_bcast<0xAA>(av);
            float go = dpp_bcast<0xFF>(av);
            c2 = gf * c2 + gi * gg;
            float h2n = go * ftanh(c2);
            if (g2 == 0) {
                h2s[w][m] = (_Float16)h2n;      // own replica (FIFO)
                if (w == 0) ring[(p - 1) & 31][m] = h2n;
            }
        }
    }
#undef DOTP

    // make wave 0's ring write for t=2047 (post-final-barrier) visible to
    // wave 1's tail reads -- THE r11/r12 bug
    __syncthreads();

    // ---- tail flush: timesteps 2032..2047 ----
    {
        const int tt = 2032 + (tid >> 3), ch0 = (tid & 7) * 2;
        float2 v = *(const float2*)&ring[tt & 31][ch0];
        *(float2*)(outb + (size_t)tt * H2 + ch0) = v;
    }
}

extern "C" void kernel_launch(void* const* d_in, const int* in_sizes, int n_in,
                              void* d_out, int out_size, void* d_ws, size_t ws_size,
                              hipStream_t stream) {
    const float* x     = (const float*)d_in[0];
    const float* w_ih1 = (const float*)d_in[1];
    const float* w_hh1 = (const float*)d_in[2];
    const float* b_ih1 = (const float*)d_in[3];
    const float* b_hh1 = (const float*)d_in[4];
    const float* w_ih2 = (const float*)d_in[5];
    const float* w_hh2 = (const float*)d_in[6];
    const float* b_ih2 = (const float*)d_in[7];
    const float* b_hh2 = (const float*)d_in[8];
    float* out = (float*)d_out;

    lstm2_fused<<<NBATCH, 128, 0, stream>>>(x, w_ih1, w_hh1, b_ih1, b_hh1,
                                            w_ih2, w_hh2, b_ih2, b_hh2, out);
}

// Round 14
// 1175.520 us; speedup vs baseline: 1.3510x; 1.3510x over previous
//
#include <hip/hip_runtime.h>

#define TSTEPS 2048
#define NBATCH 512
#define H1 64
#define H2 16

typedef _Float16 h2v __attribute__((ext_vector_type(2)));

__device__ __forceinline__ float fsig(float x) {
    return __builtin_amdgcn_rcpf(1.0f + __builtin_amdgcn_exp2f(-1.4426950408889634f * x));
}
__device__ __forceinline__ float ftanh(float x) {
    // tanh(x) = 1 - 2/(exp2(2x*log2e)+1); saturates correctly at +-inf
    return 1.0f - 2.0f * __builtin_amdgcn_rcpf(1.0f + __builtin_amdgcn_exp2f(2.8853900817779268f * x));
}
// branchless: k2==1 -> sigmoid(x); k2==2 -> tanh(x) = 2*sig(2x)-1
__device__ __forceinline__ float act(float x, float k2) {
    return k2 * fsig(k2 * x) - (k2 - 1.0f);
}

#if __has_builtin(__builtin_amdgcn_fdot2)
__device__ __forceinline__ float dot2(int wp, int hp, float acc) {
    return __builtin_amdgcn_fdot2(__builtin_bit_cast(h2v, wp),
                                  __builtin_bit_cast(h2v, hp), acc, false);
}
#else
__device__ __forceinline__ float dot2(int wp, int hp, float acc) {
    h2v a = __builtin_bit_cast(h2v, wp), b = __builtin_bit_cast(h2v, hp);
    return acc + (float)a.x * (float)b.x + (float)a.y * (float)b.y;
}
#endif

__device__ __forceinline__ int packh2(float a, float b) {
    h2v v; v.x = (_Float16)a; v.y = (_Float16)b;
    return __builtin_bit_cast(int, v);
}
template<int CTRL>
__device__ __forceinline__ float dpp_bcast(float v) {   // quad broadcast
    int r = __builtin_amdgcn_mov_dpp(__float_as_int(v), CTRL, 0xF, 0xF, true);
    return __int_as_float(r);
}

// ONE WAVE PER BATCH, ZERO BARRIERS (r9 dataflow, 1234 us baseline) with the
// register story finally clean:
//  - r13 verdict: 2-wave k-split + barrier = 1588 us > r9; barrier costs more
//    than it saves -> single-wave frame is right.
//  - ALL asm pins deleted. r9's in-loop "+v" pins demanded 168 resident
//    dwords against a 128-reg allocation -> the compiler spilled/remat'd
//    ~100 dwords/lane/step through L2 (~970 stall cyc/step, VALUBusy 33%).
//    The pins CAUSED the traffic they were meant to prevent (r3's motivation
//    was a KB-units misread of FETCH_SIZE).
//  - amdgpu_num_vgpr(256): demand ~228 (168 weights + 16 hp-chunk + ~45
//    working) fits the 256 arch file; with the budget granted, plain LICM
//    keeps loop-invariant weights resident with no pins needed.
__global__ void __launch_bounds__(64, 1)
__attribute__((amdgpu_num_vgpr(256)))
lstm2_fused(const float* __restrict__ x,      // [512, 2048, 1]
            const float* __restrict__ w_ih1,  // [256, 1]
            const float* __restrict__ w_hh1,  // [256, 64]
            const float* __restrict__ b_ih1,  // [256]
            const float* __restrict__ b_hh1,  // [256]
            const float* __restrict__ w_ih2,  // [64, 64]
            const float* __restrict__ w_hh2,  // [64, 16]
            const float* __restrict__ b_ih2,  // [64]
            const float* __restrict__ b_hh2,  // [64]
            float* __restrict__ out)          // [512, 2048, 16]
{
    const int lane = threadIdx.x;     // 64 threads = 1 wave
    const int b    = blockIdx.x;      // 1 batch per block

    __shared__ float    x_lds[TSTEPS];     // 8 KB
    __shared__ _Float16 h1_lds[H1];        // 128 B
    __shared__ _Float16 h2_lds[H2];        // 32 B
    __shared__ float    ring[32][H2];      // 2 KB output ring

    // ---- stage x[b,:] ----
    {
        const float4* xs = (const float4*)(x + (size_t)b * TSTEPS);
        float4* xd = (float4*)x_lds;
        #pragma unroll
        for (int i = 0; i < 8; ++i) xd[lane + 64 * i] = xs[lane + 64 * i];
    }
    if (lane < 32) ((int*)h1_lds)[lane] = 0;
    if (lane < 8)  ((int*)h2_lds)[lane] = 0;

    // ---- L1 weights: lane j; gate rows {j, 64+j, 128+j, 192+j}, k=0..63 ----
    int   w1[4][32];                   // packed f16 pairs (128 VGPRs)
    float wx1[4], bs1[4];
    #pragma unroll
    for (int g = 0; g < 4; ++g) {
        const int r = g * H1 + lane;
        const float* wr = w_hh1 + (size_t)r * H1;
        #pragma unroll
        for (int k = 0; k < 32; ++k) w1[g][k] = packh2(wr[2 * k], wr[2 * k + 1]);
        wx1[g] = w_ih1[r];
        bs1[g] = b_ih1[r] + b_hh1[r];
    }
    // ---- L2 weights: lane -> channel m = lane>>2, gate g2 = lane&3 ----
    const int m  = lane >> 2;
    const int g2 = lane & 3;
    const int r2 = g2 * H2 + m;
    int w2[32], wh2[8];                // 40 VGPRs
    #pragma unroll
    for (int k = 0; k < 32; ++k)
        w2[k] = packh2(w_ih2[(size_t)r2 * H1 + 2 * k], w_ih2[(size_t)r2 * H1 + 2 * k + 1]);
    #pragma unroll
    for (int k = 0; k < 8; ++k)
        wh2[k] = packh2(w_hh2[(size_t)r2 * H2 + 2 * k], w_hh2[(size_t)r2 * H2 + 2 * k + 1]);
    const float bs2 = b_ih2[r2] + b_hh2[r2];
    const float k22 = (g2 == 2) ? 2.0f : 1.0f;

    float c1 = 0.0f;                  // cell of L1 channel j (lane-private)
    float c2 = 0.0f;                  // cell of L2 channel m (replicated per quad)
    float* outb = out + (size_t)b * TSTEPS * H2;

    for (int p = 0; p <= TSTEPS; ++p) {
        // ---- output flush: every 16 steps, slots written 16-31 steps ago ----
        const int tau_f = p - 1;
        if (tau_f >= 31 && (tau_f & 15) == 15) {
            const int tau0 = (tau_f & ~15) - 16;
            const int tt = tau0 + (lane >> 2), ch0 = (lane & 3) * 4;
            float4 v = *(const float4*)&ring[tt & 31][ch0];
            *(float4*)(outb + (size_t)tt * H2 + ch0) = v;      // 1 KB coalesced
        }

        // ---- gate accumulators ----
        const float xv = x_lds[p & (TSTEPS - 1)];      // p==TSTEPS value unused
        float ai = bs1[0] + wx1[0] * xv;
        float af = bs1[1] + wx1[1] * xv;
        float ag = bs1[2] + wx1[2] * xv;
        float ao = bs1[3] + wx1[3] * xv;
        float a0 = bs2, a1 = 0.f, a2a = 0.f, a3 = 0.f;

        // ---- h1(p-1) in 2-chunk pipeline: liveness 16 regs, latency hidden ----
        {
            const int4* hs4 = (const int4*)h1_lds;
            int4 hA = hs4[0], hB = hs4[1];
            #pragma unroll
            for (int c = 0; c < 4; ++c) {
                int4 nA, nB;
                if (c < 3) { nA = hs4[2 * c + 2]; nB = hs4[2 * c + 3]; }
                const int h0 = hA.x, h1p = hA.y, h2p = hA.z, h3p = hA.w;
                const int h4p = hB.x, h5p = hB.y, h6p = hB.z, h7p = hB.w;
                // L1: 4 gate chains x 8 pairs
                ai = dot2(w1[0][8*c+0], h0, ai);  af = dot2(w1[1][8*c+0], h0, af);
                ag = dot2(w1[2][8*c+0], h0, ag);  ao = dot2(w1[3][8*c+0], h0, ao);
                ai = dot2(w1[0][8*c+1], h1p, ai); af = dot2(w1[1][8*c+1], h1p, af);
                ag = dot2(w1[2][8*c+1], h1p, ag); ao = dot2(w1[3][8*c+1], h1p, ao);
                ai = dot2(w1[0][8*c+2], h2p, ai); af = dot2(w1[1][8*c+2], h2p, af);
                ag = dot2(w1[2][8*c+2], h2p, ag); ao = dot2(w1[3][8*c+2], h2p, ao);
                ai = dot2(w1[0][8*c+3], h3p, ai); af = dot2(w1[1][8*c+3], h3p, af);
                ag = dot2(w1[2][8*c+3], h3p, ag); ao = dot2(w1[3][8*c+3], h3p, ao);
                ai = dot2(w1[0][8*c+4], h4p, ai); af = dot2(w1[1][8*c+4], h4p, af);
                ag = dot2(w1[2][8*c+4], h4p, ag); ao = dot2(w1[3][8*c+4], h4p, ao);
                ai = dot2(w1[0][8*c+5], h5p, ai); af = dot2(w1[1][8*c+5], h5p, af);
                ag = dot2(w1[2][8*c+5], h5p, ag); ao = dot2(w1[3][8*c+5], h5p, ao);
                ai = dot2(w1[0][8*c+6], h6p, ai); af = dot2(w1[1][8*c+6], h6p, af);
                ag = dot2(w1[2][8*c+6], h6p, ag); ao = dot2(w1[3][8*c+6], h6p, ao);
                ai = dot2(w1[0][8*c+7], h7p, ai); af = dot2(w1[1][8*c+7], h7p, af);
                ag = dot2(w1[2][8*c+7], h7p, ag); ao = dot2(w1[3][8*c+7], h7p, ao);
                // L2 ih-chains: 2 pairs per chain per chunk
                a0  = dot2(w2[8*c+0], h0,  a0);   a0  = dot2(w2[8*c+4], h4p, a0);
                a1  = dot2(w2[8*c+1], h1p, a1);   a1  = dot2(w2[8*c+5], h5p, a1);
                a2a = dot2(w2[8*c+2], h2p, a2a);  a2a = dot2(w2[8*c+6], h6p, a2a);
                a3  = dot2(w2[8*c+3], h3p, a3);   a3  = dot2(w2[8*c+7], h7p, a3);
                if (c < 3) { hA = nA; hB = nB; }
            }
        }

        // ===== Layer 1 finish, timestep p =====
        if (p < TSTEPS) {
            float gi = fsig(ai), gf = fsig(af), gg = ftanh(ag), go = fsig(ao);
            c1 = gf * c1 + gi * gg;
            float h1n = go * ftanh(c1);
            h1_lds[lane] = (_Float16)h1n;       // ds_write_b16; same-wave FIFO
        }

        // ===== Layer 2 finish, timestep p-1 (same wave, no sync) =====
        if (p >= 1) {
            int hq[8];
            {
                const int4* hs = (const int4*)h2_lds;   // h2(p-2)
                int4 u0 = hs[0], u1 = hs[1];
                hq[0]=u0.x; hq[1]=u0.y; hq[2]=u0.z; hq[3]=u0.w;
                hq[4]=u1.x; hq[5]=u1.y; hq[6]=u1.z; hq[7]=u1.w;
            }
            #pragma unroll
            for (int k = 0; k < 2; ++k) {       // w_hh2 (16 k)
                a0  = dot2(wh2[4*k+0], hq[4*k+0], a0);
                a1  = dot2(wh2[4*k+1], hq[4*k+1], a1);
                a2a = dot2(wh2[4*k+2], hq[4*k+2], a2a);
                a3  = dot2(wh2[4*k+3], hq[4*k+3], a3);
            }
            float av = act((a0 + a1) + (a2a + a3), k22);
            // gather the quad's 4 gates (i,f,g,o) via DPP broadcast
            float gi = dpp_bcast<0x00>(av);
            float gf = dpp_bcast<0x55>(av);
            float gg = dpp_bcast<0xAA>(av);
            float go = dpp_bcast<0xFF>(av);
            c2 = gf * c2 + gi * gg;
            float h2n = go * ftanh(c2);
            if (g2 == 0) {
                h2_lds[m] = (_Float16)h2n;
                ring[(p - 1) & 31][m] = h2n;
            }
        }
    }

    // ---- tail flush: timesteps 2032..2047 (same wave -> FIFO safe) ----
    {
        const int tt = 2032 + (lane >> 2), ch0 = (lane & 3) * 4;
        float4 v = *(const float4*)&ring[tt & 31][ch0];
        *(float4*)(outb + (size_t)tt * H2 + ch0) = v;
    }
}

extern "C" void kernel_launch(void* const* d_in, const int* in_sizes, int n_in,
                              void* d_out, int out_size, void* d_ws, size_t ws_size,
                              hipStream_t stream) {
    const float* x     = (const float*)d_in[0];
    const float* w_ih1 = (const float*)d_in[1];
    const float* w_hh1 = (const float*)d_in[2];
    const float* b_ih1 = (const float*)d_in[3];
    const float* b_hh1 = (const float*)d_in[4];
    const float* w_ih2 = (const float*)d_in[5];
    const float* w_hh2 = (const float*)d_in[6];
    const float* b_ih2 = (const float*)d_in[7];
    const float* b_hh2 = (const float*)d_in[8];
    float* out = (float*)d_out;

    lstm2_fused<<<NBATCH, 64, 0, stream>>>(x, w_ih1, w_hh1, b_ih1, b_hh1,
                                           w_ih2, w_hh2, b_ih2, b_hh2, out);
}

// Round 15
// 1173.318 us; speedup vs baseline: 1.3536x; 1.0019x over previous
//
#include <hip/hip_runtime.h>

#define TSTEPS 2048
#define NBATCH 512
#define H1 64
#define H2 16

typedef _Float16 h2v __attribute__((ext_vector_type(2)));

__device__ __forceinline__ float fsig(float x) {
    return __builtin_amdgcn_rcpf(1.0f + __builtin_amdgcn_exp2f(-1.4426950408889634f * x));
}
__device__ __forceinline__ float ftanh(float x) {
    // tanh(x) = 1 - 2/(exp2(2x*log2e)+1); saturates correctly at +-inf
    return 1.0f - 2.0f * __builtin_amdgcn_rcpf(1.0f + __builtin_amdgcn_exp2f(2.8853900817779268f * x));
}
// branchless: k2==1 -> sigmoid(x); k2==2 -> tanh(x) = 2*sig(2x)-1
__device__ __forceinline__ float act(float x, float k2) {
    return k2 * fsig(k2 * x) - (k2 - 1.0f);
}

#if __has_builtin(__builtin_amdgcn_fdot2)
__device__ __forceinline__ float dot2(int wp, int hp, float acc) {
    return __builtin_amdgcn_fdot2(__builtin_bit_cast(h2v, wp),
                                  __builtin_bit_cast(h2v, hp), acc, false);
}
#else
__device__ __forceinline__ float dot2(int wp, int hp, float acc) {
    h2v a = __builtin_bit_cast(h2v, wp), b = __builtin_bit_cast(h2v, hp);
    return acc + (float)a.x * (float)b.x + (float)a.y * (float)b.y;
}
#endif

__device__ __forceinline__ int packh2(float a, float b) {
    h2v v; v.x = (_Float16)a; v.y = (_Float16)b;
    return __builtin_bit_cast(int, v);
}
template<int CTRL>
__device__ __forceinline__ float dpp_bcast(float v) {   // quad broadcast
    int r = __builtin_amdgcn_mov_dpp(__float_as_int(v), CTRL, 0xF, 0xF, true);
    return __int_as_float(r);
}

// ONE WAVE PER BATCH, ZERO BARRIERS (r9/r14 dataflow) with the register
// overflow moved to the LDS pipe instead of L2:
// r14 verdict: allocator holds ~132 VGPRs vs ~212 demand -> ~80 dwords/lane/
// step re-streamed from L2 (~20 KB/step/wave at ~56 B/cyc/CU + exposed
// latency) = the ~950-cyc gap (1450 measured vs ~480 issue, VALUBusy 34%).
// Fix: registers keep only w1 gates i,f (64 dwords) + working. Gates g,o and
// ALL L2 weights (104 dwords/lane) are staged once into LDS [tq][lane]
// (each lane reads only its own column -> no sync; coalesced b128) and
// streamed per chunk: 26 ds_read_b128/step on the 256 B/clk DS pipe,
// overlapping the VALU dots. Demand ~139 ~= budget -> no L2 streaming.
__global__ void __launch_bounds__(64, 1)
__attribute__((amdgpu_waves_per_eu(1, 1)))
lstm2_fused(const float* __restrict__ x,      // [512, 2048, 1]
            const float* __restrict__ w_ih1,  // [256, 1]
            const float* __restrict__ w_hh1,  // [256, 64]
            const float* __restrict__ b_ih1,  // [256]
            const float* __restrict__ b_hh1,  // [256]
            const float* __restrict__ w_ih2,  // [64, 64]
            const float* __restrict__ w_hh2,  // [64, 16]
            const float* __restrict__ b_ih2,  // [64]
            const float* __restrict__ b_hh2,  // [64]
            float* __restrict__ out)          // [512, 2048, 16]
{
    const int lane = threadIdx.x;     // 64 threads = 1 wave
    const int b    = blockIdx.x;      // 1 batch per block

    __shared__ int4     wlds[26][64];      // 26.6 KB streamed weights
    __shared__ float    x_lds[TSTEPS];     // 8 KB
    __shared__ _Float16 h1_lds[H1];        // 128 B
    __shared__ _Float16 h2_lds[H2];        // 32 B
    __shared__ float    ring[32][H2];      // 2 KB output ring

    // ---- stage x[b,:] ----
    {
        const float4* xs = (const float4*)(x + (size_t)b * TSTEPS);
        float4* xd = (float4*)x_lds;
        #pragma unroll
        for (int i = 0; i < 8; ++i) xd[lane + 64 * i] = xs[lane + 64 * i];
    }
    if (lane < 32) ((int*)h1_lds)[lane] = 0;
    if (lane < 8)  ((int*)h2_lds)[lane] = 0;

    // ---- register-resident L1 weights: gates i (row lane), f (row 64+lane) ----
    int w1i[32], w1f[32];
    {
        const float* wri = w_hh1 + (size_t)lane * H1;
        const float* wrf = w_hh1 + (size_t)(H1 + lane) * H1;
        #pragma unroll
        for (int k = 0; k < 32; ++k) {
            w1i[k] = packh2(wri[2 * k], wri[2 * k + 1]);
            w1f[k] = packh2(wrf[2 * k], wrf[2 * k + 1]);
        }
    }
    // ---- LDS-streamed weights: w1 gate g (tq 0..7), gate o (tq 8..15),
    //      w2 (tq 16..23), wh2 (tq 24..25). Lane-private columns. ----
    const int m  = lane >> 2;
    const int g2 = lane & 3;
    const int r2 = g2 * H2 + m;
    {
        const float* wrg = w_hh1 + (size_t)(2 * H1 + lane) * H1;
        const float* wro = w_hh1 + (size_t)(3 * H1 + lane) * H1;
        const float* wr2 = w_ih2 + (size_t)r2 * H1;
        #pragma unroll
        for (int tq = 0; tq < 8; ++tq) {
            wlds[tq][lane] = make_int4(
                packh2(wrg[8*tq+0], wrg[8*tq+1]), packh2(wrg[8*tq+2], wrg[8*tq+3]),
                packh2(wrg[8*tq+4], wrg[8*tq+5]), packh2(wrg[8*tq+6], wrg[8*tq+7]));
            wlds[8 + tq][lane] = make_int4(
                packh2(wro[8*tq+0], wro[8*tq+1]), packh2(wro[8*tq+2], wro[8*tq+3]),
                packh2(wro[8*tq+4], wro[8*tq+5]), packh2(wro[8*tq+6], wro[8*tq+7]));
            wlds[16 + tq][lane] = make_int4(
                packh2(wr2[8*tq+0], wr2[8*tq+1]), packh2(wr2[8*tq+2], wr2[8*tq+3]),
                packh2(wr2[8*tq+4], wr2[8*tq+5]), packh2(wr2[8*tq+6], wr2[8*tq+7]));
        }
        const float* wrh = w_hh2 + (size_t)r2 * H2;
        wlds[24][lane] = make_int4(packh2(wrh[0], wrh[1]),  packh2(wrh[2], wrh[3]),
                                   packh2(wrh[4], wrh[5]),  packh2(wrh[6], wrh[7]));
        wlds[25][lane] = make_int4(packh2(wrh[8], wrh[9]),  packh2(wrh[10], wrh[11]),
                                   packh2(wrh[12], wrh[13]), packh2(wrh[14], wrh[15]));
    }

    // ---- per-gate scalars ----
    const float wxi = w_ih1[lane],        wxf = w_ih1[H1 + lane];
    const float wxg = w_ih1[2*H1 + lane], wxo = w_ih1[3*H1 + lane];
    const float bsi = b_ih1[lane] + b_hh1[lane];
    const float bsf = b_ih1[H1+lane] + b_hh1[H1+lane];
    const float bsg = b_ih1[2*H1+lane] + b_hh1[2*H1+lane];
    const float bso = b_ih1[3*H1+lane] + b_hh1[3*H1+lane];
    const float bs2 = b_ih2[r2] + b_hh2[r2];
    const float k22 = (g2 == 2) ? 2.0f : 1.0f;

    float c1 = 0.0f;                  // cell of L1 channel `lane`
    float c2 = 0.0f;                  // cell of L2 channel m (replicated per quad)
    float* outb = out + (size_t)b * TSTEPS * H2;

    const int4* wl = &wlds[0][0];     // index tq*64 + lane

    for (int p = 0; p <= TSTEPS; ++p) {
        // ---- output flush: every 16 steps, slots written 16-31 steps ago ----
        const int tau_f = p - 1;
        if (tau_f >= 31 && (tau_f & 15) == 15) {
            const int tau0 = (tau_f & ~15) - 16;
            const int tt = tau0 + (lane >> 2), ch0 = (lane & 3) * 4;
            float4 v = *(const float4*)&ring[tt & 31][ch0];
            *(float4*)(outb + (size_t)tt * H2 + ch0) = v;      // 1 KB coalesced
        }

        // ---- gate accumulators ----
        const float xv = x_lds[p & (TSTEPS - 1)];      // p==TSTEPS value unused
        float ai = bsi + wxi * xv;
        float af = bsf + wxf * xv;
        float ag = bsg + wxg * xv;
        float ao = bso + wxo * xv;
        float a0 = bs2, a1 = 0.f, a2a = 0.f, a3 = 0.f;
        int4 vh0, vh1;                 // wh2, loaded during chunk 2

        // ---- 4 chunks of 8 h-pairs; weights g/o/w2 streamed from LDS ----
        {
            const int4* hs4 = (const int4*)h1_lds;
            #pragma unroll
            for (int c = 0; c < 4; ++c) {
                int4 hA = hs4[2*c], hB = hs4[2*c + 1];
                int4 cg  = wl[(2*c)      * 64 + lane];
                int4 cg2 = wl[(2*c + 1)  * 64 + lane];
                int4 co  = wl[(8 + 2*c)  * 64 + lane];
                int4 co2 = wl[(9 + 2*c)  * 64 + lane];
                int4 cu  = wl[(16 + 2*c) * 64 + lane];
                int4 cu2 = wl[(17 + 2*c) * 64 + lane];
                if (c == 2) { vh0 = wl[24 * 64 + lane]; vh1 = wl[25 * 64 + lane]; }

                ai = dot2(w1i[8*c+0], hA.x, ai); ai = dot2(w1i[8*c+1], hA.y, ai);
                ai = dot2(w1i[8*c+2], hA.z, ai); ai = dot2(w1i[8*c+3], hA.w, ai);
                ai = dot2(w1i[8*c+4], hB.x, ai); ai = dot2(w1i[8*c+5], hB.y, ai);
                ai = dot2(w1i[8*c+6], hB.z, ai); ai = dot2(w1i[8*c+7], hB.w, ai);

                af = dot2(w1f[8*c+0], hA.x, af); af = dot2(w1f[8*c+1], hA.y, af);
                af = dot2(w1f[8*c+2], hA.z, af); af = dot2(w1f[8*c+3], hA.w, af);
                af = dot2(w1f[8*c+4], hB.x, af); af = dot2(w1f[8*c+5], hB.y, af);
                af = dot2(w1f[8*c+6], hB.z, af); af = dot2(w1f[8*c+7], hB.w, af);

                ag = dot2(cg.x,  hA.x, ag); ag = dot2(cg.y,  hA.y, ag);
                ag = dot2(cg.z,  hA.z, ag); ag = dot2(cg.w,  hA.w, ag);
                ag = dot2(cg2.x, hB.x, ag); ag = dot2(cg2.y, hB.y, ag);
                ag = dot2(cg2.z, hB.z, ag); ag = dot2(cg2.w, hB.w, ag);

                ao = dot2(co.x,  hA.x, ao); ao = dot2(co.y,  hA.y, ao);
                ao = dot2(co.z,  hA.z, ao); ao = dot2(co.w,  hA.w, ao);
                ao = dot2(co2.x, hB.x, ao); ao = dot2(co2.y, hB.y, ao);
                ao = dot2(co2.z, hB.z, ao); ao = dot2(co2.w, hB.w, ao);

                a0  = dot2(cu.x,  hA.x, a0);  a1  = dot2(cu.y,  hA.y, a1);
                a2a = dot2(cu.z,  hA.z, a2a); a3  = dot2(cu.w,  hA.w, a3);
                a0  = dot2(cu2.x, hB.x, a0);  a1  = dot2(cu2.y, hB.y, a1);
                a2a = dot2(cu2.z, hB.z, a2a); a3  = dot2(cu2.w, hB.w, a3);
            }
        }

        // ===== Layer 1 finish, timestep p =====
        if (p < TSTEPS) {
            float gi = fsig(ai), gf = fsig(af), gg = ftanh(ag), go = fsig(ao);
            c1 = gf * c1 + gi * gg;
            float h1n = go * ftanh(c1);
            h1_lds[lane] = (_Float16)h1n;       // ds_write_b16; same-wave FIFO
        }

        // ===== Layer 2 finish, timestep p-1 (same wave, no sync) =====
        if (p >= 1) {
            const int4* hs = (const int4*)h2_lds;   // h2(p-2)
            int4 u0 = hs[0], u1 = hs[1];
            a0  = dot2(vh0.x, u0.x, a0);  a1  = dot2(vh0.y, u0.y, a1);
            a2a = dot2(vh0.z, u0.z, a2a); a3  = dot2(vh0.w, u0.w, a3);
            a0  = dot2(vh1.x, u1.x, a0);  a1  = dot2(vh1.y, u1.y, a1);
            a2a = dot2(vh1.z, u1.z, a2a); a3  = dot2(vh1.w, u1.w, a3);
            float av = act((a0 + a1) + (a2a + a3), k22);
            // gather the quad's 4 gates (i,f,g,o) via DPP broadcast
            float gi = dpp_bcast<0x00>(av);
            float gf = dpp_bcast<0x55>(av);
            float gg = dpp_bcast<0xAA>(av);
            float go = dpp_bcast<0xFF>(av);
            c2 = gf * c2 + gi * gg;
            float h2n = go * ftanh(c2);
            if (g2 == 0) {
                h2_lds[m] = (_Float16)h2n;
                ring[(p - 1) & 31][m] = h2n;
            }
        }
    }

    // ---- tail flush: timesteps 2032..2047 (same wave -> FIFO safe) ----
    {
        const int tt = 2032 + (lane >> 2), ch0 = (lane & 3) * 4;
        float4 v = *(const float4*)&ring[tt & 31][ch0];
        *(float4*)(outb + (size_t)tt * H2 + ch0) = v;
    }
}

extern "C" void kernel_launch(void* const* d_in, const int* in_sizes, int n_in,
                              void* d_out, int out_size, void* d_ws, size_t ws_size,
                              hipStream_t stream) {
    const float* x     = (const float*)d_in[0];
    const float* w_ih1 = (const float*)d_in[1];
    const float* w_hh1 = (const float*)d_in[2];
    const float* b_ih1 = (const float*)d_in[3];
    const float* b_hh1 = (const float*)d_in[4];
    const float* w_ih2 = (const float*)d_in[5];
    const float* w_hh2 = (const float*)d_in[6];
    const float* b_ih2 = (const float*)d_in[7];
    const float* b_hh2 = (const float*)d_in[8];
    float* out = (float*)d_out;

    lstm2_fused<<<NBATCH, 64, 0, stream>>>(x, w_ih1, w_hh1, b_ih1, b_hh1,
                                           w_ih2, w_hh2, b_ih2, b_hh2, out);
}